// Round 6
// baseline (289.742 us; speedup 1.0000x reference)
//
#include <hip/hip_runtime.h>
#include <hip/hip_bf16.h>

#define DI __device__ __forceinline__

typedef __bf16 bf16x8 __attribute__((ext_vector_type(8)));
typedef float  f32x4  __attribute__((ext_vector_type(4)));

DI unsigned short f2bf(float f) {
    unsigned int u = __float_as_uint(f);
    u += 0x7fffu + ((u >> 16) & 1u);
    return (unsigned short)(u >> 16);
}

DI void gload16(const unsigned short* g, unsigned short* l) {
    __builtin_amdgcn_global_load_lds(
        (const __attribute__((address_space(1))) unsigned int*)g,
        (__attribute__((address_space(3))) unsigned int*)l, 16, 0, 0);
}

// ---------------------------------------------------------------------------
__global__ void convert_x(const float* __restrict__ x, unsigned short* __restrict__ Xb) {
    int i = blockIdx.x * 256 + threadIdx.x;
    float4 v = reinterpret_cast<const float4*>(x)[i];
    ushort4 o;
    o.x = f2bf(v.x); o.y = f2bf(v.y); o.z = f2bf(v.z); o.w = f2bf(v.w);
    reinterpret_cast<ushort4*>(Xb)[i] = o;
}

__global__ void convert_w(const float* __restrict__ Wq, const float* __restrict__ Wk,
                          const float* __restrict__ Wv, unsigned short* __restrict__ Wt) {
    __shared__ float t[32][33];
    const int z = blockIdx.z;
    const float* W = (z == 0) ? Wq : (z == 1 ? Wk : Wv);
    const float scale = (z == 0) ? 0.03125f : 1.0f;
    const int n0 = blockIdx.x * 32, k0 = blockIdx.y * 32;
    const int tx = threadIdx.x, ty = threadIdx.y;
#pragma unroll
    for (int i = 0; i < 4; ++i)
        t[ty + i * 8][tx] = W[(size_t)(k0 + ty + i * 8) * 1024 + n0 + tx];
    __syncthreads();
#pragma unroll
    for (int i = 0; i < 4; ++i)
        Wt[(size_t)(z * 1024 + n0 + ty + i * 8) * 1024 + k0 + tx] =
            f2bf(t[tx][ty + i * 8] * scale);
}

// ---------------------------------------------------------------------------
// MODE 0: 256x256x(BK=64) 4-phase NT GEMM (unchanged from round 4, passing).
// Collective-wait invariant: ALL certification flows through the single
// pre-BAR WAITV4 at p3 (drains both kt+1 halves for every wave before the
// barrier that precedes their first read).
// ---------------------------------------------------------------------------

#define BAR    asm volatile("s_barrier" ::: "memory")
#define WAITV4 asm volatile("s_waitcnt vmcnt(4)" ::: "memory")
#define WAITV2 asm volatile("s_waitcnt vmcnt(2)" ::: "memory")
#define WAITV1 asm volatile("s_waitcnt vmcnt(1)" ::: "memory")
#define WAITV0 asm volatile("s_waitcnt vmcnt(0)" ::: "memory")

#define READ_A(SLOT, MH)                                                      \
    _Pragma("unroll")                                                         \
    for (int fi = 0; fi < 4; ++fi)                                            \
        _Pragma("unroll")                                                     \
        for (int kk = 0; kk < 2; ++kk)                                        \
            aR[fi][kk] = *reinterpret_cast<const bf16x8*>(                    \
                lsA + (SLOT) * 16384 + (MH) * 8192 +                          \
                ((abase ^ (kk * 32)) + fi * 1024));

#define READ_B(SLOT, NH, BS)                                                  \
    _Pragma("unroll")                                                         \
    for (int fj = 0; fj < 2; ++fj)                                            \
        _Pragma("unroll")                                                     \
        for (int kk = 0; kk < 2; ++kk)                                        \
            BS[fj][kk] = *reinterpret_cast<const bf16x8*>(                    \
                lsB + (SLOT) * 16384 + (NH) * 8192 +                          \
                ((bbase ^ (kk * 32)) + fj * 1024));

#define STAGE_A(KT, H)                                                        \
    {                                                                         \
        unsigned uA_ = (unsigned)(m0 + (H) * 128) * 1024u + (unsigned)(KT) * 64u; \
        _Pragma("unroll")                                                     \
        for (int it = 0; it < 2; ++it)                                        \
            gload16(Ab + uA_ + sAoff[it],                                     \
                    lsA + (((KT) & 1) * 2 + (H)) * 8192 + it * 4096 + tid * 8);\
    }

#define STAGE_B(KT, H)                                                        \
    {                                                                         \
        unsigned uB_ = (unsigned)(n0 + (H) * 128) * 1024u + (unsigned)(KT) * 64u; \
        _Pragma("unroll")                                                     \
        for (int it = 0; it < 2; ++it)                                        \
            gload16(Bb + uB_ + sBoff[it],                                     \
                    lsB + (((KT) & 1) * 2 + (H)) * 8192 + it * 4096 + tid * 8);\
    }

#define MMA_PHASE(MH, NH, BS)                                                 \
    __builtin_amdgcn_s_setprio(1);                                            \
    _Pragma("unroll")                                                         \
    for (int kk = 0; kk < 2; ++kk)                                            \
        _Pragma("unroll")                                                     \
        for (int fi = 0; fi < 4; ++fi)                                        \
            _Pragma("unroll")                                                 \
            for (int fj = 0; fj < 2; ++fj)                                    \
                acc[(MH) * 4 + fi][(NH) * 2 + fj] =                           \
                    __builtin_amdgcn_mfma_f32_16x16x32_bf16(                  \
                        aR[fi][kk], BS[fj][kk],                               \
                        acc[(MH) * 4 + fi][(NH) * 2 + fj], 0, 0, 0);          \
    __builtin_amdgcn_s_setprio(0);

__global__ __launch_bounds__(512) void gemm256(
    const unsigned short* __restrict__ A0, const unsigned short* __restrict__ B0,
    unsigned short* __restrict__ Oq, unsigned short* __restrict__ Ok,
    unsigned short* __restrict__ Ov)
{
    extern __shared__ char smem_raw[];
    unsigned short* lsA = (unsigned short*)smem_raw;
    unsigned short* lsB = lsA + 32768;

    const int tid = threadIdx.x;
    const int lane = tid & 63;
    const int wid = tid >> 6;
    const int wm = wid >> 2, wn = wid & 3;
    const int lr = lane & 15, lg = lane >> 4;

    const int m0 = blockIdx.x * 256, n0 = blockIdx.y * 256;
    const int NT = 16;
    const unsigned short* Ab = A0;
    const unsigned short* Bb = B0;

    const unsigned chm = (unsigned)(lg ^ (lr & 7));
    const unsigned abase = (unsigned)(wm * 64 + lr) * 64u + chm * 8u;
    const unsigned bbase = (unsigned)(wn * 32 + lr) * 64u + chm * 8u;
    unsigned sAoff[2], sBoff[2];
#pragma unroll
    for (int it = 0; it < 2; ++it) {
        const unsigned idx = it * 512 + tid;
        const unsigned row = idx >> 3;
        const unsigned ch = (idx & 7) ^ (row & 7);
        sAoff[it] = row * 1024u + ch * 8u;
        sBoff[it] = row * 1024u + ch * 8u;
    }

    f32x4 acc[8][4] = {};
    bf16x8 aR[4][2], b0[2][2], b1[2][2];

    STAGE_A(0, 0); STAGE_A(0, 1); STAGE_B(0, 0); STAGE_B(0, 1);
    STAGE_A(1, 0); STAGE_B(1, 0);
    WAITV4; BAR;

    for (int kt = 0; kt < NT; ++kt) {
        const int slot = kt & 1;
        const bool s1 = (kt + 1) < NT, s2 = (kt + 2) < NT;
        READ_A(slot, 0); READ_B(slot, 0, b0);
        if (s1) { STAGE_A(kt + 1, 1); }
        BAR; MMA_PHASE(0, 0, b0);
        READ_B(slot, 1, b1);
        if (s1) { STAGE_B(kt + 1, 1); }
        BAR; MMA_PHASE(0, 1, b1);
        READ_A(slot, 1);
        if (s2) { STAGE_A(kt + 2, 0); }
        BAR; MMA_PHASE(1, 0, b0);
        if (s2) {
            STAGE_B(kt + 2, 0);
            WAITV4;
        } else {
            WAITV0;
        }
        BAR; MMA_PHASE(1, 1, b1);
    }

#pragma unroll
    for (int i = 0; i < 8; ++i) {
        const int rl = (i >> 2) * 128 + wm * 64 + (i & 3) * 16 + lg * 4;
#pragma unroll
        for (int j = 0; j < 4; ++j) {
            const int cl = (j >> 1) * 128 + wn * 32 + (j & 1) * 16 + lr;
            f32x4 v = acc[i][j];
            const int gm = m0 + rl;
            const int z = n0 >> 10;
            const int cin = (n0 & 1023) + cl;
            if (z == 2) {
                const int b = gm >> 11, nib = gm & 2047;
                ushort4 h;
                h.x = f2bf(v[0]); h.y = f2bf(v[1]); h.z = f2bf(v[2]); h.w = f2bf(v[3]);
                *reinterpret_cast<ushort4*>(
                    &Ov[(size_t)b * 2097152u + (size_t)cin * 2048 + nib]) = h;
            } else {
                unsigned short* O = z ? Ok : Oq;
#pragma unroll
                for (int r2 = 0; r2 < 4; ++r2)
                    O[(size_t)(gm + r2) * 1024 + cin] = f2bf(v[r2]);
            }
        }
    }
}

// ---------------------------------------------------------------------------
// Attention GEMMs: 128x256 tile, BK=32, 8 waves (2Mx4N), 48 KiB LDS,
// 2 blocks/CU. ROUND 6 FIX: every counted vmcnt moved to BEFORE the phase's
// s_barrier so it is a COLLECTIVE guarantee (each wave drains its own loads,
// barrier publishes all) — round 5 had the waits after the barrier, which
// certifies only the waiting wave's loads -> cross-wave race -> inf.
// Ledger (wave-local FIFO, 3 loads in flight steady-state):
//   prologue: stage A0,Blo0,Bhi0; WAITV1 (drain A0,Blo0); BAR
//   p0: read A,Blo(slot); stage A,Blo(kt+1); WAITV2 (drain Bhi(kt)) | tail V0; BAR; MFMA-lo
//   p1: read Bhi(slot);   stage Bhi(kt+1);   WAITV1 (drain A,Blo(kt+1)) | tail V0; BAR; MFMA-hi
// Stage targets the opposite slot; last reads of every staged region are
// >=2 barriers + ~500cy global latency before the write can land.
// ---------------------------------------------------------------------------
template <int MODE>
__global__ __launch_bounds__(512, 4) void gemm_attn(
    const unsigned short* __restrict__ A0, const unsigned short* __restrict__ B0,
    float* __restrict__ Cf)
{
    __shared__ alignas(16) unsigned short lds[2 * 12288];  // slot: A 4096 + B 8192 elems

    const int tid = threadIdx.x;
    const int lane = tid & 63;
    const int wid = tid >> 6;
    const int wm = wid >> 2, wn = wid & 3;
    const int lr = lane & 15, lg = lane >> 4;

    int r128, n0, NT, bz;
    const unsigned short *Ab, *Bb;
    size_t cbase;
    constexpr unsigned STRB = (MODE == 2) ? 2048u : 1024u;

    if constexpr (MODE == 1) {
        const int c256 = blockIdx.x;
        r128 = blockIdx.y; bz = blockIdx.z;
        if (c256 > (r128 >> 1)) return;
        n0 = c256 * 256; NT = 32;
        const int r256 = r128 >> 1;
        Ab = A0 + (size_t)bz * 2097152u;
        Bb = B0 + (size_t)bz * 2097152u;
        cbase = ((size_t)bz * 36 + (size_t)(r256 * (r256 + 1) / 2) + c256) * 65536u +
                (size_t)(r128 & 1) * 32768u;
    } else {
        const int idx = blockIdx.x;          // longest-first: r128 descending
        r128 = 15 - (idx >> 5);
        const int nt4 = (idx >> 3) & 3;
        bz = idx & 7;
        n0 = nt4 * 256; NT = 4 * (r128 + 1);
        const int r256 = r128 >> 1;
        Ab = A0 + ((size_t)bz * 36 + (size_t)(r256 * (r256 + 1) / 2)) * 65536u;
        Bb = B0 + (size_t)bz * 2097152u;
        cbase = (size_t)bz * 2097152u + (size_t)(r128 * 128) * 1024u;
    }

    const unsigned fswl = (unsigned)((lr ^ (lr >> 2)) & 3);
    const unsigned abase = (unsigned)(wm * 64 + lr) * 32u + ((unsigned)lg ^ fswl) * 8u;
    const unsigned bbase = 4096u + (unsigned)(wn * 32 + lr) * 32u + ((unsigned)lg ^ fswl) * 8u;

    const unsigned rowA = (unsigned)(tid >> 2);
    const unsigned chA = ((unsigned)tid & 3u) ^ (unsigned)((rowA ^ (rowA >> 2)) & 3u);
    unsigned sAoff;
    if constexpr (MODE == 1)
        sAoff = ((unsigned)(r128 * 128) + rowA) * 1024u + chA * 8u;
    else
        sAoff = ((unsigned)((r128 & 1) * 128) + rowA) * 256u + chA * 8u;
    unsigned sBoff[2];
#pragma unroll
    for (int it = 0; it < 2; ++it) {
        const unsigned idx = it * 512 + tid;
        const unsigned rowB = idx >> 2;
        const unsigned chB = (idx & 3u) ^ (unsigned)((rowB ^ (rowB >> 2)) & 3u);
        sBoff[it] = ((unsigned)n0 + rowB) * STRB + chB * 8u;
    }

#define AT_STAGE_A(KT)                                                        \
    {                                                                         \
        unsigned u_;                                                          \
        if constexpr (MODE == 2)                                              \
            u_ = ((unsigned)((KT) >> 3)) * 65536u + ((KT) & 7) * 32u;         \
        else                                                                  \
            u_ = (unsigned)(KT) * 32u;                                        \
        gload16(Ab + u_ + sAoff, lds + ((KT) & 1) * 12288 + tid * 8);         \
    }
#define AT_STAGE_B(KT, IT)                                                    \
    gload16(Bb + (unsigned)(KT) * 32u + sBoff[IT],                            \
            lds + ((KT) & 1) * 12288 + 4096 + (IT) * 4096 + tid * 8);

    f32x4 acc[4][4] = {};
    bf16x8 aR[4], bv[2];

    AT_STAGE_A(0); AT_STAGE_B(0, 0); AT_STAGE_B(0, 1);
    WAITV1; BAR;                    // collective: A0 + B-lo0 resident

    for (int kt = 0; kt < NT; ++kt) {
        const int slot = kt & 1;
        const bool s1 = (kt + 1) < NT;
        const unsigned sb = (unsigned)slot * 12288u;
        // ---- phase 0: A + B-lo ----
#pragma unroll
        for (int fi = 0; fi < 4; ++fi)
            aR[fi] = *reinterpret_cast<const bf16x8*>(lds + sb + abase + fi * 512);
#pragma unroll
        for (int fj = 0; fj < 2; ++fj)
            bv[fj] = *reinterpret_cast<const bf16x8*>(lds + sb + bbase + fj * 512);
        if (s1) { AT_STAGE_A(kt + 1); AT_STAGE_B(kt + 1, 0); WAITV2; }
        else    { WAITV0; }
        BAR;
        __builtin_amdgcn_s_setprio(1);
#pragma unroll
        for (int fi = 0; fi < 4; ++fi)
#pragma unroll
            for (int fj = 0; fj < 2; ++fj)
                acc[fi][fj] = __builtin_amdgcn_mfma_f32_16x16x32_bf16(
                    aR[fi], bv[fj], acc[fi][fj], 0, 0, 0);
        __builtin_amdgcn_s_setprio(0);
        // ---- phase 1: B-hi ----
#pragma unroll
        for (int fj = 0; fj < 2; ++fj)
            bv[fj] = *reinterpret_cast<const bf16x8*>(lds + sb + bbase + 4096 + fj * 512);
        if (s1) { AT_STAGE_B(kt + 1, 1); WAITV1; }
        else    { WAITV0; }
        BAR;
        __builtin_amdgcn_s_setprio(1);
#pragma unroll
        for (int fi = 0; fi < 4; ++fi)
#pragma unroll
            for (int fj = 0; fj < 2; ++fj)
                acc[fi][2 + fj] = __builtin_amdgcn_mfma_f32_16x16x32_bf16(
                    aR[fi], bv[fj], acc[fi][2 + fj], 0, 0, 0);
        __builtin_amdgcn_s_setprio(0);
    }

    // epilogue: D frag layout col=lr, row=lg*4+r2
#pragma unroll
    for (int fi = 0; fi < 4; ++fi) {
        const int rloc = wm * 64 + fi * 16 + lg * 4;
#pragma unroll
        for (int j = 0; j < 4; ++j) {
            const int cloc = (j >> 1) * 128 + wn * 32 + (j & 1) * 16 + lr;
            f32x4 v = acc[fi][j];
            if constexpr (MODE == 1) {
#pragma unroll
                for (int r2 = 0; r2 < 4; ++r2)
                    Cf[cbase + (size_t)(rloc + r2) * 256 + cloc] = v[r2];
            } else {
#pragma unroll
                for (int r2 = 0; r2 < 4; ++r2)
                    Cf[cbase + (size_t)(rloc + r2) * 1024 + (n0 + cloc)] = v[r2];
            }
        }
    }
#undef AT_STAGE_A
#undef AT_STAGE_B
}

// ---------------------------------------------------------------------------
// row softmax over packed causal 256x256 S tiles -> packed bf16 P
// ---------------------------------------------------------------------------
__global__ __launch_bounds__(256) void softmax_rows(const float* __restrict__ Sp,
                                                    unsigned short* __restrict__ Pp) {
    const int R = blockIdx.x;
    const int b = blockIdx.y;
    const int rt = R >> 8;
    const size_t rowbase = ((size_t)b * 36 + (size_t)(rt * (rt + 1) / 2)) * 65536u +
                           (size_t)(R & 255) * 256;
    const int tid = threadIdx.x;
    const int kend = (rt + 1) << 8;

    float vals[8];
    float m = -3.0e38f;
    int cnt = 0;
    for (int k = tid; k < kend; k += 256) {
        float s = Sp[rowbase + (size_t)(k >> 8) * 65536u + (k & 255)];
        vals[cnt++] = s;
        if (k <= R) m = fmaxf(m, s);
    }
    __shared__ float red[4];
#pragma unroll
    for (int o = 32; o > 0; o >>= 1) m = fmaxf(m, __shfl_xor(m, o));
    if ((tid & 63) == 0) red[tid >> 6] = m;
    __syncthreads();
    m = fmaxf(fmaxf(red[0], red[1]), fmaxf(red[2], red[3]));
    __syncthreads();

    float l = 0.0f;
    cnt = 0;
    for (int k = tid; k < kend; k += 256) {
        float e = (k <= R) ? __expf(vals[cnt] - m) : 0.0f;
        vals[cnt] = e;
        ++cnt;
        l += e;
    }
#pragma unroll
    for (int o = 32; o > 0; o >>= 1) l += __shfl_xor(l, o);
    if ((tid & 63) == 0) red[tid >> 6] = l;
    __syncthreads();
    l = red[0] + red[1] + red[2] + red[3];
    const float inv = 1.0f / l;

    cnt = 0;
    for (int k = tid; k < kend; k += 256)
        Pp[rowbase + (size_t)(k >> 8) * 65536u + (k & 255)] = f2bf(vals[cnt++] * inv);
}

// ---------------------------------------------------------------------------
extern "C" void kernel_launch(void* const* d_in, const int* in_sizes, int n_in,
                              void* d_out, int out_size, void* d_ws, size_t ws_size,
                              hipStream_t stream) {
    const float* x  = (const float*)d_in[0];
    const float* Wq = (const float*)d_in[1];
    const float* Wk = (const float*)d_in[2];
    const float* Wv = (const float*)d_in[3];
    float* out = (float*)d_out;

    char* base = (char*)d_ws;
    unsigned short* Qb = (unsigned short*)(base);
    unsigned short* Kb = (unsigned short*)(base + 33554432u);
    unsigned short* Vt = (unsigned short*)(base + 67108864u);
    unsigned short* Xb = (unsigned short*)(base + 100663296u);
    unsigned short* Wt = (unsigned short*)(base + 134217728u);
    float*          Sp = (float*)         (base + 100663296u);   // overlays Xb/Wt
    unsigned short* Pp = (unsigned short*)(base + 176160768u);

    hipFuncSetAttribute(reinterpret_cast<const void*>(&gemm256),
                        hipFuncAttributeMaxDynamicSharedMemorySize, 131072);

    convert_x<<<16384, 256, 0, stream>>>(x, Xb);
    convert_w<<<dim3(32, 32, 3), dim3(32, 8), 0, stream>>>(Wq, Wk, Wv, Wt);
    gemm256<<<dim3(64, 12), 512, 131072, stream>>>(Xb, Wt, Qb, Kb, Vt);
    gemm_attn<1><<<dim3(8, 16, 8), 512, 0, stream>>>(Qb, Kb, Sp);
    softmax_rows<<<dim3(2048, 8), 256, 0, stream>>>(Sp, Pp);
    gemm_attn<2><<<512, 512, 0, stream>>>(Pp, Vt, out);
}

// Round 7
// 287.877 us; speedup vs baseline: 1.0065x; 1.0065x over previous
//
#include <hip/hip_runtime.h>
#include <hip/hip_bf16.h>

#define DI __device__ __forceinline__

typedef __bf16 bf16x8 __attribute__((ext_vector_type(8)));
typedef float  f32x4  __attribute__((ext_vector_type(4)));

DI unsigned short f2bf(float f) {
    unsigned int u = __float_as_uint(f);
    u += 0x7fffu + ((u >> 16) & 1u);
    return (unsigned short)(u >> 16);
}

DI void gload16(const unsigned short* g, unsigned short* l) {
    __builtin_amdgcn_global_load_lds(
        (const __attribute__((address_space(1))) unsigned int*)g,
        (__attribute__((address_space(3))) unsigned int*)l, 16, 0, 0);
}

// ---------------------------------------------------------------------------
__global__ void convert_x(const float* __restrict__ x, unsigned short* __restrict__ Xb) {
    int i = blockIdx.x * 256 + threadIdx.x;
    float4 v = reinterpret_cast<const float4*>(x)[i];
    ushort4 o;
    o.x = f2bf(v.x); o.y = f2bf(v.y); o.z = f2bf(v.z); o.w = f2bf(v.w);
    reinterpret_cast<ushort4*>(Xb)[i] = o;
}

__global__ void convert_w(const float* __restrict__ Wq, const float* __restrict__ Wk,
                          const float* __restrict__ Wv, unsigned short* __restrict__ Wt) {
    __shared__ float t[32][33];
    const int z = blockIdx.z;
    const float* W = (z == 0) ? Wq : (z == 1 ? Wk : Wv);
    const float scale = (z == 0) ? 0.03125f : 1.0f;
    const int n0 = blockIdx.x * 32, k0 = blockIdx.y * 32;
    const int tx = threadIdx.x, ty = threadIdx.y;
#pragma unroll
    for (int i = 0; i < 4; ++i)
        t[ty + i * 8][tx] = W[(size_t)(k0 + ty + i * 8) * 1024 + n0 + tx];
    __syncthreads();
#pragma unroll
    for (int i = 0; i < 4; ++i)
        Wt[(size_t)(z * 1024 + n0 + ty + i * 8) * 1024 + k0 + tx] =
            f2bf(t[tx][ty + i * 8] * scale);
}

// ---------------------------------------------------------------------------
// MODE 0: 256x256x(BK=64) 4-phase NT GEMM (unchanged from round 4, passing).
// ---------------------------------------------------------------------------

#define BAR    asm volatile("s_barrier" ::: "memory")
#define WAITV4 asm volatile("s_waitcnt vmcnt(4)" ::: "memory")
#define WAITV3 asm volatile("s_waitcnt vmcnt(3)" ::: "memory")
#define WAITV0 asm volatile("s_waitcnt vmcnt(0)" ::: "memory")

#define READ_A(SLOT, MH)                                                      \
    _Pragma("unroll")                                                         \
    for (int fi = 0; fi < 4; ++fi)                                            \
        _Pragma("unroll")                                                     \
        for (int kk = 0; kk < 2; ++kk)                                        \
            aR[fi][kk] = *reinterpret_cast<const bf16x8*>(                    \
                lsA + (SLOT) * 16384 + (MH) * 8192 +                          \
                ((abase ^ (kk * 32)) + fi * 1024));

#define READ_B(SLOT, NH, BS)                                                  \
    _Pragma("unroll")                                                         \
    for (int fj = 0; fj < 2; ++fj)                                            \
        _Pragma("unroll")                                                     \
        for (int kk = 0; kk < 2; ++kk)                                        \
            BS[fj][kk] = *reinterpret_cast<const bf16x8*>(                    \
                lsB + (SLOT) * 16384 + (NH) * 8192 +                          \
                ((bbase ^ (kk * 32)) + fj * 1024));

#define STAGE_A(KT, H)                                                        \
    {                                                                         \
        unsigned uA_ = (unsigned)(m0 + (H) * 128) * 1024u + (unsigned)(KT) * 64u; \
        _Pragma("unroll")                                                     \
        for (int it = 0; it < 2; ++it)                                        \
            gload16(Ab + uA_ + sAoff[it],                                     \
                    lsA + (((KT) & 1) * 2 + (H)) * 8192 + it * 4096 + tid * 8);\
    }

#define STAGE_B(KT, H)                                                        \
    {                                                                         \
        unsigned uB_ = (unsigned)(n0 + (H) * 128) * 1024u + (unsigned)(KT) * 64u; \
        _Pragma("unroll")                                                     \
        for (int it = 0; it < 2; ++it)                                        \
            gload16(Bb + uB_ + sBoff[it],                                     \
                    lsB + (((KT) & 1) * 2 + (H)) * 8192 + it * 4096 + tid * 8);\
    }

#define MMA_PHASE(MH, NH, BS)                                                 \
    __builtin_amdgcn_s_setprio(1);                                            \
    _Pragma("unroll")                                                         \
    for (int kk = 0; kk < 2; ++kk)                                            \
        _Pragma("unroll")                                                     \
        for (int fi = 0; fi < 4; ++fi)                                        \
            _Pragma("unroll")                                                 \
            for (int fj = 0; fj < 2; ++fj)                                    \
                acc[(MH) * 4 + fi][(NH) * 2 + fj] =                           \
                    __builtin_amdgcn_mfma_f32_16x16x32_bf16(                  \
                        aR[fi][kk], BS[fj][kk],                               \
                        acc[(MH) * 4 + fi][(NH) * 2 + fj], 0, 0, 0);          \
    __builtin_amdgcn_s_setprio(0);

__global__ __launch_bounds__(512) void gemm256(
    const unsigned short* __restrict__ A0, const unsigned short* __restrict__ B0,
    unsigned short* __restrict__ Oq, unsigned short* __restrict__ Ok,
    unsigned short* __restrict__ Ov)
{
    extern __shared__ char smem_raw[];
    unsigned short* lsA = (unsigned short*)smem_raw;
    unsigned short* lsB = lsA + 32768;

    const int tid = threadIdx.x;
    const int lane = tid & 63;
    const int wid = tid >> 6;
    const int wm = wid >> 2, wn = wid & 3;
    const int lr = lane & 15, lg = lane >> 4;

    const int m0 = blockIdx.x * 256, n0 = blockIdx.y * 256;
    const int NT = 16;
    const unsigned short* Ab = A0;
    const unsigned short* Bb = B0;

    const unsigned chm = (unsigned)(lg ^ (lr & 7));
    const unsigned abase = (unsigned)(wm * 64 + lr) * 64u + chm * 8u;
    const unsigned bbase = (unsigned)(wn * 32 + lr) * 64u + chm * 8u;
    unsigned sAoff[2], sBoff[2];
#pragma unroll
    for (int it = 0; it < 2; ++it) {
        const unsigned idx = it * 512 + tid;
        const unsigned row = idx >> 3;
        const unsigned ch = (idx & 7) ^ (row & 7);
        sAoff[it] = row * 1024u + ch * 8u;
        sBoff[it] = row * 1024u + ch * 8u;
    }

    f32x4 acc[8][4] = {};
    bf16x8 aR[4][2], b0[2][2], b1[2][2];

    STAGE_A(0, 0); STAGE_A(0, 1); STAGE_B(0, 0); STAGE_B(0, 1);
    STAGE_A(1, 0); STAGE_B(1, 0);
    WAITV4; BAR;

    for (int kt = 0; kt < NT; ++kt) {
        const int slot = kt & 1;
        const bool s1 = (kt + 1) < NT, s2 = (kt + 2) < NT;
        READ_A(slot, 0); READ_B(slot, 0, b0);
        if (s1) { STAGE_A(kt + 1, 1); }
        BAR; MMA_PHASE(0, 0, b0);
        READ_B(slot, 1, b1);
        if (s1) { STAGE_B(kt + 1, 1); }
        BAR; MMA_PHASE(0, 1, b1);
        READ_A(slot, 1);
        if (s2) { STAGE_A(kt + 2, 0); }
        BAR; MMA_PHASE(1, 0, b0);
        if (s2) {
            STAGE_B(kt + 2, 0);
            WAITV4;
        } else {
            WAITV0;
        }
        BAR; MMA_PHASE(1, 1, b1);
    }

#pragma unroll
    for (int i = 0; i < 8; ++i) {
        const int rl = (i >> 2) * 128 + wm * 64 + (i & 3) * 16 + lg * 4;
#pragma unroll
        for (int j = 0; j < 4; ++j) {
            const int cl = (j >> 1) * 128 + wn * 32 + (j & 1) * 16 + lr;
            f32x4 v = acc[i][j];
            const int gm = m0 + rl;
            const int z = n0 >> 10;
            const int cin = (n0 & 1023) + cl;
            if (z == 2) {
                const int b = gm >> 11, nib = gm & 2047;
                ushort4 h;
                h.x = f2bf(v[0]); h.y = f2bf(v[1]); h.z = f2bf(v[2]); h.w = f2bf(v[3]);
                *reinterpret_cast<ushort4*>(
                    &Ov[(size_t)b * 2097152u + (size_t)cin * 2048 + nib]) = h;
            } else {
                unsigned short* O = z ? Ok : Oq;
#pragma unroll
                for (int r2 = 0; r2 < 4; ++r2)
                    O[(size_t)(gm + r2) * 1024 + cin] = f2bf(v[r2]);
            }
        }
    }
}

// ---------------------------------------------------------------------------
// Attention GEMMs, ROUND 7: 128x256 tile, BK=32, 8 waves, 3-SLOT LDS (72 KiB,
// 2 blocks/CU). Stage distance = 2 K-tiles ahead (3-4 phases ~= 2100+ cyc >>
// 900-cyc HBM latency) so the single per-kt WAITV3 (pre-BAR, collective)
// never stalls — round 6 staged kt+1 (1 phase, ~700 cyc) and stalled every
// phase. Ledger (3 gloads/wave/kt): steady outstanding at p1-wait = 6
// (kt+1's 3 + kt+2's 3) -> WAITV3 drains exactly kt+1; tail: WAITV0 at
// kt=NT-2; nothing outstanding at NT-1. WAR safety: stage at kt targets slot
// (kt+2)%3 = slot(kt-1), whose last reads are separated by 2 barriers with
// an intervening MFMA whose lgkm-wait certifies read COMPLETION (provable,
// unlike round 6's 1-barrier issued-only separation).
// MODE 1: S=Q@K^T causal. MODE 2: O=P@Vt^T, PAIRED: each block runs row-
// panels r=pr and r=15-pr sequentially -> uniform 68 kt/block, 256 blocks.
// ---------------------------------------------------------------------------
template <int MODE>
__global__ __launch_bounds__(512, 4) void gemm_attn(
    const unsigned short* __restrict__ A0, const unsigned short* __restrict__ B0,
    float* __restrict__ Cf)
{
    __shared__ alignas(16) unsigned short lds[3 * 12288];  // slot: A 4096 + B 8192 elems

    const int tid = threadIdx.x;
    const int lane = tid & 63;
    const int wid = tid >> 6;
    const int wm = wid >> 2, wn = wid & 3;
    const int lr = lane & 15, lg = lane >> 4;

    int n0, bz, pr = 0, r128_0 = 0;
    constexpr unsigned STRB = (MODE == 2) ? 2048u : 1024u;

    if constexpr (MODE == 1) {
        const int c256 = blockIdx.x;
        r128_0 = blockIdx.y; bz = blockIdx.z;
        if (c256 > (r128_0 >> 1)) return;
        n0 = c256 * 256;
    } else {
        const int idx = blockIdx.x;          // 256 blocks: 8 pr x 4 nt x 8 bz
        pr = idx >> 5;
        const int nt4 = (idx >> 3) & 3;
        bz = idx & 7;
        n0 = nt4 * 256;
    }
    const unsigned short* Bb = B0 + (size_t)bz * 2097152u;

    const unsigned fswl = (unsigned)((lr ^ (lr >> 2)) & 3);
    const unsigned abase = (unsigned)(wm * 64 + lr) * 32u + ((unsigned)lg ^ fswl) * 8u;
    const unsigned bbase = 4096u + (unsigned)(wn * 32 + lr) * 32u + ((unsigned)lg ^ fswl) * 8u;

    const unsigned rowA = (unsigned)(tid >> 2);
    const unsigned chA = ((unsigned)tid & 3u) ^ (unsigned)((rowA ^ (rowA >> 2)) & 3u);
    unsigned sBoff[2];
#pragma unroll
    for (int it = 0; it < 2; ++it) {
        const unsigned idx = it * 512 + tid;
        const unsigned rowB = idx >> 2;
        const unsigned chB = (idx & 3u) ^ (unsigned)((rowB ^ (rowB >> 2)) & 3u);
        sBoff[it] = ((unsigned)n0 + rowB) * STRB + chB * 8u;
    }

#define AT_STAGE_A(KT, SL)                                                    \
    {                                                                         \
        unsigned u_;                                                          \
        if constexpr (MODE == 2)                                              \
            u_ = ((unsigned)((KT) >> 3)) * 65536u + ((KT) & 7) * 32u;         \
        else                                                                  \
            u_ = (unsigned)(KT) * 32u;                                        \
        gload16(Ab + u_ + sAoff, lds + (SL) * 12288 + tid * 8);               \
    }
#define AT_STAGE_B(KT, SL, IT)                                                \
    gload16(Bb + (unsigned)(KT) * 32u + sBoff[IT],                            \
            lds + (SL) * 12288 + 4096 + (IT) * 4096 + tid * 8);

    const int nhalf = (MODE == 2) ? 2 : 1;
    for (int half = 0; half < nhalf; ++half) {
        const int r128 = (MODE == 1) ? r128_0 : (half ? 15 - pr : pr);
        const int NT = (MODE == 1) ? 32 : 4 * (r128 + 1);
        const int r256 = r128 >> 1;

        const unsigned short* Ab;
        size_t cbase;
        unsigned sAoff;
        if constexpr (MODE == 1) {
            Ab = A0 + (size_t)bz * 2097152u;
            cbase = ((size_t)bz * 36 + (size_t)(r256 * (r256 + 1) / 2) + (n0 >> 8)) * 65536u +
                    (size_t)(r128 & 1) * 32768u;
            sAoff = ((unsigned)(r128 * 128) + rowA) * 1024u + chA * 8u;
        } else {
            Ab = A0 + ((size_t)bz * 36 + (size_t)(r256 * (r256 + 1) / 2)) * 65536u;
            cbase = (size_t)bz * 2097152u + (size_t)(r128 * 128) * 1024u;
            sAoff = ((unsigned)((r128 & 1) * 128) + rowA) * 256u + chA * 8u;
        }

        if (half) BAR;   // certify half-0's final reads complete before restage

        f32x4 acc[4][4] = {};
        bf16x8 aR[4], bv[2];

        // prologue: kt0 -> slot0, kt1 -> slot1 (NT >= 4 always)
        AT_STAGE_A(0, 0); AT_STAGE_B(0, 0, 0); AT_STAGE_B(0, 0, 1);
        AT_STAGE_A(1, 1); AT_STAGE_B(1, 1, 0); AT_STAGE_B(1, 1, 1);
        WAITV3; BAR;                    // kt0 resident collectively

        for (int kt = 0; kt < NT; ++kt) {
            const int sl = kt % 3;
            const int sl2 = (kt + 2) % 3;
            const bool s1 = (kt + 1) < NT, s2 = (kt + 2) < NT;
            const unsigned sb = (unsigned)sl * 12288u;
            // ---- phase 0: A + B-lo ----
#pragma unroll
            for (int fi = 0; fi < 4; ++fi)
                aR[fi] = *reinterpret_cast<const bf16x8*>(lds + sb + abase + fi * 512);
#pragma unroll
            for (int fj = 0; fj < 2; ++fj)
                bv[fj] = *reinterpret_cast<const bf16x8*>(lds + sb + bbase + fj * 512);
            if (s2) { AT_STAGE_A(kt + 2, sl2); AT_STAGE_B(kt + 2, sl2, 0); }
            BAR;
            __builtin_amdgcn_s_setprio(1);
#pragma unroll
            for (int fi = 0; fi < 4; ++fi)
#pragma unroll
                for (int fj = 0; fj < 2; ++fj)
                    acc[fi][fj] = __builtin_amdgcn_mfma_f32_16x16x32_bf16(
                        aR[fi], bv[fj], acc[fi][fj], 0, 0, 0);
            __builtin_amdgcn_s_setprio(0);
            // ---- phase 1: B-hi ----
#pragma unroll
            for (int fj = 0; fj < 2; ++fj)
                bv[fj] = *reinterpret_cast<const bf16x8*>(lds + sb + bbase + 4096 + fj * 512);
            if (s2) { AT_STAGE_B(kt + 2, sl2, 1); WAITV3; }
            else if (s1) { WAITV0; }
            BAR;
            __builtin_amdgcn_s_setprio(1);
#pragma unroll
            for (int fi = 0; fi < 4; ++fi)
#pragma unroll
                for (int fj = 0; fj < 2; ++fj)
                    acc[fi][2 + fj] = __builtin_amdgcn_mfma_f32_16x16x32_bf16(
                        aR[fi], bv[fj], acc[fi][2 + fj], 0, 0, 0);
            __builtin_amdgcn_s_setprio(0);
        }

        // epilogue: D frag layout col=lr, row=lg*4+r2
#pragma unroll
        for (int fi = 0; fi < 4; ++fi) {
            const int rloc = wm * 64 + fi * 16 + lg * 4;
#pragma unroll
            for (int j = 0; j < 4; ++j) {
                const int cloc = (j >> 1) * 128 + wn * 32 + (j & 1) * 16 + lr;
                f32x4 v = acc[fi][j];
                if constexpr (MODE == 1) {
#pragma unroll
                    for (int r2 = 0; r2 < 4; ++r2)
                        Cf[cbase + (size_t)(rloc + r2) * 256 + cloc] = v[r2];
                } else {
#pragma unroll
                    for (int r2 = 0; r2 < 4; ++r2)
                        Cf[cbase + (size_t)(rloc + r2) * 1024 + (n0 + cloc)] = v[r2];
                }
            }
        }
    }
#undef AT_STAGE_A
#undef AT_STAGE_B
}

// ---------------------------------------------------------------------------
// row softmax over packed causal 256x256 S tiles -> packed bf16 P
// ---------------------------------------------------------------------------
__global__ __launch_bounds__(256) void softmax_rows(const float* __restrict__ Sp,
                                                    unsigned short* __restrict__ Pp) {
    const int R = blockIdx.x;
    const int b = blockIdx.y;
    const int rt = R >> 8;
    const size_t rowbase = ((size_t)b * 36 + (size_t)(rt * (rt + 1) / 2)) * 65536u +
                           (size_t)(R & 255) * 256;
    const int tid = threadIdx.x;
    const int kend = (rt + 1) << 8;

    float vals[8];
    float m = -3.0e38f;
    int cnt = 0;
    for (int k = tid; k < kend; k += 256) {
        float s = Sp[rowbase + (size_t)(k >> 8) * 65536u + (k & 255)];
        vals[cnt++] = s;
        if (k <= R) m = fmaxf(m, s);
    }
    __shared__ float red[4];
#pragma unroll
    for (int o = 32; o > 0; o >>= 1) m = fmaxf(m, __shfl_xor(m, o));
    if ((tid & 63) == 0) red[tid >> 6] = m;
    __syncthreads();
    m = fmaxf(fmaxf(red[0], red[1]), fmaxf(red[2], red[3]));
    __syncthreads();

    float l = 0.0f;
    cnt = 0;
    for (int k = tid; k < kend; k += 256) {
        float e = (k <= R) ? __expf(vals[cnt] - m) : 0.0f;
        vals[cnt] = e;
        ++cnt;
        l += e;
    }
#pragma unroll
    for (int o = 32; o > 0; o >>= 1) l += __shfl_xor(l, o);
    if ((tid & 63) == 0) red[tid >> 6] = l;
    __syncthreads();
    l = red[0] + red[1] + red[2] + red[3];
    const float inv = 1.0f / l;

    cnt = 0;
    for (int k = tid; k < kend; k += 256)
        Pp[rowbase + (size_t)(k >> 8) * 65536u + (k & 255)] = f2bf(vals[cnt++] * inv);
}

// ---------------------------------------------------------------------------
extern "C" void kernel_launch(void* const* d_in, const int* in_sizes, int n_in,
                              void* d_out, int out_size, void* d_ws, size_t ws_size,
                              hipStream_t stream) {
    const float* x  = (const float*)d_in[0];
    const float* Wq = (const float*)d_in[1];
    const float* Wk = (const float*)d_in[2];
    const float* Wv = (const float*)d_in[3];
    float* out = (float*)d_out;

    char* base = (char*)d_ws;
    unsigned short* Qb = (unsigned short*)(base);
    unsigned short* Kb = (unsigned short*)(base + 33554432u);
    unsigned short* Vt = (unsigned short*)(base + 67108864u);
    unsigned short* Xb = (unsigned short*)(base + 100663296u);
    unsigned short* Wt = (unsigned short*)(base + 134217728u);
    float*          Sp = (float*)         (base + 100663296u);   // overlays Xb/Wt
    unsigned short* Pp = (unsigned short*)(base + 176160768u);

    hipFuncSetAttribute(reinterpret_cast<const void*>(&gemm256),
                        hipFuncAttributeMaxDynamicSharedMemorySize, 131072);

    convert_x<<<16384, 256, 0, stream>>>(x, Xb);
    convert_w<<<dim3(32, 32, 3), dim3(32, 8), 0, stream>>>(Wq, Wk, Wv, Wt);
    gemm256<<<dim3(64, 12), 512, 131072, stream>>>(Xb, Wt, Qb, Kb, Vt);
    gemm_attn<1><<<dim3(8, 16, 8), 512, 0, stream>>>(Qb, Kb, Sp);
    softmax_rows<<<dim3(2048, 8), 256, 0, stream>>>(Sp, Pp);
    gemm_attn<2><<<256, 512, 0, stream>>>(Pp, Vt, out);
}

// Round 8
// 282.807 us; speedup vs baseline: 1.0245x; 1.0179x over previous
//
#include <hip/hip_runtime.h>
#include <hip/hip_bf16.h>

#define DI __device__ __forceinline__

typedef __bf16 bf16x8 __attribute__((ext_vector_type(8)));
typedef float  f32x4  __attribute__((ext_vector_type(4)));

DI unsigned short f2bf(float f) {
    unsigned int u = __float_as_uint(f);
    u += 0x7fffu + ((u >> 16) & 1u);
    return (unsigned short)(u >> 16);
}

DI void gload16(const unsigned short* g, unsigned short* l) {
    __builtin_amdgcn_global_load_lds(
        (const __attribute__((address_space(1))) unsigned int*)g,
        (__attribute__((address_space(3))) unsigned int*)l, 16, 0, 0);
}

// ---------------------------------------------------------------------------
__global__ void convert_x(const float* __restrict__ x, unsigned short* __restrict__ Xb) {
    int i = blockIdx.x * 256 + threadIdx.x;
    float4 v = reinterpret_cast<const float4*>(x)[i];
    ushort4 o;
    o.x = f2bf(v.x); o.y = f2bf(v.y); o.z = f2bf(v.z); o.w = f2bf(v.w);
    reinterpret_cast<ushort4*>(Xb)[i] = o;
}

__global__ void convert_w(const float* __restrict__ Wq, const float* __restrict__ Wk,
                          const float* __restrict__ Wv, unsigned short* __restrict__ Wt) {
    __shared__ float t[32][33];
    const int z = blockIdx.z;
    const float* W = (z == 0) ? Wq : (z == 1 ? Wk : Wv);
    const float scale = (z == 0) ? 0.03125f : 1.0f;
    const int n0 = blockIdx.x * 32, k0 = blockIdx.y * 32;
    const int tx = threadIdx.x, ty = threadIdx.y;
#pragma unroll
    for (int i = 0; i < 4; ++i)
        t[ty + i * 8][tx] = W[(size_t)(k0 + ty + i * 8) * 1024 + n0 + tx];
    __syncthreads();
#pragma unroll
    for (int i = 0; i < 4; ++i)
        Wt[(size_t)(z * 1024 + n0 + ty + i * 8) * 1024 + k0 + tx] =
            f2bf(t[tx][ty + i * 8] * scale);
}

// ---------------------------------------------------------------------------
// ROUND 8: desync schedule — ONE barrier per K-tile. Body(kt):
//   [WAITV0 (drains stage(kt), issued a full kt ~2700cy earlier -> no stall);
//    BAR (publishes slot kt resident AND certifies reads(kt-1) complete,
//         since each wave's MFMA(kt-1) lgkm-gated on them before reaching BAR);
//    stage(kt+1) -> slot^1 (just certified free);
//    reads(kt) + MFMA(kt), NO internal barriers]
// After BAR the 8 waves desynchronize: fine-grained compiler lgkmcnt lets
// each wave's MFMA start after its first reads, so the block-wide LDS burst
// (~2300cy) overlaps the MFMA stream (~2480cy) instead of serializing
// (round 4-7 structure: reads->BAR->MFMA serialized them; measured 5150cy/kt
// = sum of per-phase burst+MFMA, matching counters exactly).
// ---------------------------------------------------------------------------

#define BAR    asm volatile("s_barrier" ::: "memory")
#define WAITV3 asm volatile("s_waitcnt vmcnt(3)" ::: "memory")
#define WAITV0 asm volatile("s_waitcnt vmcnt(0)" ::: "memory")

#define READ_A(SLOT, MH)                                                      \
    _Pragma("unroll")                                                         \
    for (int fi = 0; fi < 4; ++fi)                                            \
        _Pragma("unroll")                                                     \
        for (int kk = 0; kk < 2; ++kk)                                        \
            aR[fi][kk] = *reinterpret_cast<const bf16x8*>(                    \
                lsA + (SLOT) * 16384 + (MH) * 8192 +                          \
                ((abase ^ (kk * 32)) + fi * 1024));

#define READ_B(SLOT, NH, BS)                                                  \
    _Pragma("unroll")                                                         \
    for (int fj = 0; fj < 2; ++fj)                                            \
        _Pragma("unroll")                                                     \
        for (int kk = 0; kk < 2; ++kk)                                        \
            BS[fj][kk] = *reinterpret_cast<const bf16x8*>(                    \
                lsB + (SLOT) * 16384 + (NH) * 8192 +                          \
                ((bbase ^ (kk * 32)) + fj * 1024));

#define STAGE_A(KT, H)                                                        \
    {                                                                         \
        unsigned uA_ = (unsigned)(m0 + (H) * 128) * 1024u + (unsigned)(KT) * 64u; \
        _Pragma("unroll")                                                     \
        for (int it = 0; it < 2; ++it)                                        \
            gload16(Ab + uA_ + sAoff[it],                                     \
                    lsA + (((KT) & 1) * 2 + (H)) * 8192 + it * 4096 + tid * 8);\
    }

#define STAGE_B(KT, H)                                                        \
    {                                                                         \
        unsigned uB_ = (unsigned)(n0 + (H) * 128) * 1024u + (unsigned)(KT) * 64u; \
        _Pragma("unroll")                                                     \
        for (int it = 0; it < 2; ++it)                                        \
            gload16(Bb + uB_ + sBoff[it],                                     \
                    lsB + (((KT) & 1) * 2 + (H)) * 8192 + it * 4096 + tid * 8);\
    }

#define STAGE_ALL(KT)                                                         \
    STAGE_A(KT, 0); STAGE_A(KT, 1); STAGE_B(KT, 0); STAGE_B(KT, 1);

#define MMA_PHASE(MH, NH, BS)                                                 \
    __builtin_amdgcn_s_setprio(1);                                            \
    _Pragma("unroll")                                                         \
    for (int kk = 0; kk < 2; ++kk)                                            \
        _Pragma("unroll")                                                     \
        for (int fi = 0; fi < 4; ++fi)                                        \
            _Pragma("unroll")                                                 \
            for (int fj = 0; fj < 2; ++fj)                                    \
                acc[(MH) * 4 + fi][(NH) * 2 + fj] =                           \
                    __builtin_amdgcn_mfma_f32_16x16x32_bf16(                  \
                        aR[fi][kk], BS[fj][kk],                               \
                        acc[(MH) * 4 + fi][(NH) * 2 + fj], 0, 0, 0);          \
    __builtin_amdgcn_s_setprio(0);

// full K-step: quadrant-ordered reads interleaved with MFMA, no barriers.
#define KSTEP(SLOT)                                                           \
    READ_A(SLOT, 0); READ_B(SLOT, 0, b0);                                     \
    MMA_PHASE(0, 0, b0);                                                      \
    READ_B(SLOT, 1, b1);                                                      \
    MMA_PHASE(0, 1, b1);                                                      \
    READ_A(SLOT, 1);                                                          \
    MMA_PHASE(1, 0, b0);                                                      \
    MMA_PHASE(1, 1, b1);

__global__ __launch_bounds__(512) void gemm256(
    const unsigned short* __restrict__ A0, const unsigned short* __restrict__ B0,
    unsigned short* __restrict__ Oq, unsigned short* __restrict__ Ok,
    unsigned short* __restrict__ Ov)
{
    extern __shared__ char smem_raw[];
    unsigned short* lsA = (unsigned short*)smem_raw;
    unsigned short* lsB = lsA + 32768;

    const int tid = threadIdx.x;
    const int lane = tid & 63;
    const int wid = tid >> 6;
    const int wm = wid >> 2, wn = wid & 3;
    const int lr = lane & 15, lg = lane >> 4;

    const int m0 = blockIdx.x * 256, n0 = blockIdx.y * 256;
    const int NT = 16;
    const unsigned short* Ab = A0;
    const unsigned short* Bb = B0;

    const unsigned chm = (unsigned)(lg ^ (lr & 7));
    const unsigned abase = (unsigned)(wm * 64 + lr) * 64u + chm * 8u;
    const unsigned bbase = (unsigned)(wn * 32 + lr) * 64u + chm * 8u;
    unsigned sAoff[2], sBoff[2];
#pragma unroll
    for (int it = 0; it < 2; ++it) {
        const unsigned idx = it * 512 + tid;
        const unsigned row = idx >> 3;
        const unsigned ch = (idx & 7) ^ (row & 7);
        sAoff[it] = row * 1024u + ch * 8u;
        sBoff[it] = row * 1024u + ch * 8u;
    }

    f32x4 acc[8][4] = {};
    bf16x8 aR[4][2], b0[2][2], b1[2][2];

    STAGE_ALL(0);

    for (int kt = 0; kt < NT; kt += 2) {
        WAITV0; BAR;                         // slot0 resident; reads(kt-1) certified
        if (kt + 1 < NT) { STAGE_ALL(kt + 1); }
        KSTEP(0);
        WAITV0; BAR;                         // slot1 resident; reads(kt) certified
        if (kt + 2 < NT) { STAGE_ALL(kt + 2); }
        if (kt + 1 < NT) { KSTEP(1); }
    }

#pragma unroll
    for (int i = 0; i < 8; ++i) {
        const int rl = (i >> 2) * 128 + wm * 64 + (i & 3) * 16 + lg * 4;
#pragma unroll
        for (int j = 0; j < 4; ++j) {
            const int cl = (j >> 1) * 128 + wn * 32 + (j & 1) * 16 + lr;
            f32x4 v = acc[i][j];
            const int gm = m0 + rl;
            const int z = n0 >> 10;
            const int cin = (n0 & 1023) + cl;
            if (z == 2) {
                const int b = gm >> 11, nib = gm & 2047;
                ushort4 h;
                h.x = f2bf(v[0]); h.y = f2bf(v[1]); h.z = f2bf(v[2]); h.w = f2bf(v[3]);
                *reinterpret_cast<ushort4*>(
                    &Ov[(size_t)b * 2097152u + (size_t)cin * 2048 + nib]) = h;
            } else {
                unsigned short* O = z ? Ok : Oq;
#pragma unroll
                for (int r2 = 0; r2 < 4; ++r2)
                    O[(size_t)(gm + r2) * 1024 + cin] = f2bf(v[r2]);
            }
        }
    }
}

// ---------------------------------------------------------------------------
// Attention GEMMs, ROUND 8: same desync schedule. 128x256 tile, BK=32,
// 8 waves, 3-slot LDS (72 KiB, 2 blocks/CU). Body(kt):
//   [(kt+1<NT ? WAITV3 : WAITV0)  — drains stage(kt), issued 2 kt earlier;
//    BAR; stage(kt+2) -> slot(kt+2)%3 (= slot(kt-1), certified by BAR);
//    reads(kt) + MFMA, no internal barriers]
// MODE 1: S=Q@K^T causal. MODE 2: O=P@Vt^T, 512 blocks (2/CU), longest-first.
// ---------------------------------------------------------------------------
template <int MODE>
__global__ __launch_bounds__(512, 4) void gemm_attn(
    const unsigned short* __restrict__ A0, const unsigned short* __restrict__ B0,
    float* __restrict__ Cf)
{
    __shared__ alignas(16) unsigned short lds[3 * 12288];  // slot: A 4096 + B 8192 elems

    const int tid = threadIdx.x;
    const int lane = tid & 63;
    const int wid = tid >> 6;
    const int wm = wid >> 2, wn = wid & 3;
    const int lr = lane & 15, lg = lane >> 4;

    int r128, n0, NT, bz;
    constexpr unsigned STRB = (MODE == 2) ? 2048u : 1024u;

    if constexpr (MODE == 1) {
        const int c256 = blockIdx.x;
        r128 = blockIdx.y; bz = blockIdx.z;
        if (c256 > (r128 >> 1)) return;
        n0 = c256 * 256; NT = 32;
    } else {
        const int idx = blockIdx.x;          // 512 blocks, longest-first
        r128 = 15 - (idx >> 5);
        const int nt4 = (idx >> 3) & 3;
        bz = idx & 7;
        n0 = nt4 * 256; NT = 4 * (r128 + 1);
    }
    const int r256 = r128 >> 1;
    const unsigned short* Bb = B0 + (size_t)bz * 2097152u;

    const unsigned short* Ab;
    size_t cbase;
    if constexpr (MODE == 1) {
        Ab = A0 + (size_t)bz * 2097152u;
        cbase = ((size_t)bz * 36 + (size_t)(r256 * (r256 + 1) / 2) + (n0 >> 8)) * 65536u +
                (size_t)(r128 & 1) * 32768u;
    } else {
        Ab = A0 + ((size_t)bz * 36 + (size_t)(r256 * (r256 + 1) / 2)) * 65536u;
        cbase = (size_t)bz * 2097152u + (size_t)(r128 * 128) * 1024u;
    }

    const unsigned fswl = (unsigned)((lr ^ (lr >> 2)) & 3);
    const unsigned abase = (unsigned)(wm * 64 + lr) * 32u + ((unsigned)lg ^ fswl) * 8u;
    const unsigned bbase = 4096u + (unsigned)(wn * 32 + lr) * 32u + ((unsigned)lg ^ fswl) * 8u;

    const unsigned rowA = (unsigned)(tid >> 2);
    const unsigned chA = ((unsigned)tid & 3u) ^ (unsigned)((rowA ^ (rowA >> 2)) & 3u);
    unsigned sAoff;
    if constexpr (MODE == 1)
        sAoff = ((unsigned)(r128 * 128) + rowA) * 1024u + chA * 8u;
    else
        sAoff = ((unsigned)((r128 & 1) * 128) + rowA) * 256u + chA * 8u;
    unsigned sBoff[2];
#pragma unroll
    for (int it = 0; it < 2; ++it) {
        const unsigned idx = it * 512 + tid;
        const unsigned rowB = idx >> 2;
        const unsigned chB = (idx & 3u) ^ (unsigned)((rowB ^ (rowB >> 2)) & 3u);
        sBoff[it] = ((unsigned)n0 + rowB) * STRB + chB * 8u;
    }

#define AT_STAGE(KT, SL)                                                      \
    {                                                                         \
        unsigned u_;                                                          \
        if constexpr (MODE == 2)                                              \
            u_ = ((unsigned)((KT) >> 3)) * 65536u + ((KT) & 7) * 32u;         \
        else                                                                  \
            u_ = (unsigned)(KT) * 32u;                                        \
        gload16(Ab + u_ + sAoff, lds + (SL) * 12288 + tid * 8);               \
        gload16(Bb + (unsigned)(KT) * 32u + sBoff[0],                         \
                lds + (SL) * 12288 + 4096 + tid * 8);                         \
        gload16(Bb + (unsigned)(KT) * 32u + sBoff[1],                         \
                lds + (SL) * 12288 + 8192 + tid * 8);                         \
    }

    f32x4 acc[4][4] = {};
    bf16x8 aR[4], bv[2];

    AT_STAGE(0, 0); AT_STAGE(1, 1);

    int sl = 0, st2 = 2;
    for (int kt = 0; kt < NT; ++kt) {
        if (kt + 1 < NT) { WAITV3; } else { WAITV0; }
        BAR;
        if (kt + 2 < NT) { AT_STAGE(kt + 2, st2); }
        const unsigned short* sp = lds + sl * 12288;
#pragma unroll
        for (int fi = 0; fi < 4; ++fi)
            aR[fi] = *reinterpret_cast<const bf16x8*>(sp + abase + fi * 512);
#pragma unroll
        for (int fj = 0; fj < 2; ++fj)
            bv[fj] = *reinterpret_cast<const bf16x8*>(sp + bbase + fj * 512);
        __builtin_amdgcn_s_setprio(1);
#pragma unroll
        for (int fi = 0; fi < 4; ++fi)
#pragma unroll
            for (int fj = 0; fj < 2; ++fj)
                acc[fi][fj] = __builtin_amdgcn_mfma_f32_16x16x32_bf16(
                    aR[fi], bv[fj], acc[fi][fj], 0, 0, 0);
        __builtin_amdgcn_s_setprio(0);
#pragma unroll
        for (int fj = 0; fj < 2; ++fj)
            bv[fj] = *reinterpret_cast<const bf16x8*>(sp + bbase + 4096 + fj * 512);
        __builtin_amdgcn_s_setprio(1);
#pragma unroll
        for (int fi = 0; fi < 4; ++fi)
#pragma unroll
            for (int fj = 0; fj < 2; ++fj)
                acc[fi][2 + fj] = __builtin_amdgcn_mfma_f32_16x16x32_bf16(
                    aR[fi], bv[fj], acc[fi][2 + fj], 0, 0, 0);
        __builtin_amdgcn_s_setprio(0);
        sl = (sl == 2) ? 0 : sl + 1;
        st2 = (st2 == 2) ? 0 : st2 + 1;
    }

    // epilogue: D frag layout col=lr, row=lg*4+r2
#pragma unroll
    for (int fi = 0; fi < 4; ++fi) {
        const int rloc = wm * 64 + fi * 16 + lg * 4;
#pragma unroll
        for (int j = 0; j < 4; ++j) {
            const int cloc = (j >> 1) * 128 + wn * 32 + (j & 1) * 16 + lr;
            f32x4 v = acc[fi][j];
            if constexpr (MODE == 1) {
#pragma unroll
                for (int r2 = 0; r2 < 4; ++r2)
                    Cf[cbase + (size_t)(rloc + r2) * 256 + cloc] = v[r2];
            } else {
#pragma unroll
                for (int r2 = 0; r2 < 4; ++r2)
                    Cf[cbase + (size_t)(rloc + r2) * 1024 + (n0 + cloc)] = v[r2];
            }
        }
    }
#undef AT_STAGE
}

// ---------------------------------------------------------------------------
// row softmax over packed causal 256x256 S tiles -> packed bf16 P
// ---------------------------------------------------------------------------
__global__ __launch_bounds__(256) void softmax_rows(const float* __restrict__ Sp,
                                                    unsigned short* __restrict__ Pp) {
    const int R = blockIdx.x;
    const int b = blockIdx.y;
    const int rt = R >> 8;
    const size_t rowbase = ((size_t)b * 36 + (size_t)(rt * (rt + 1) / 2)) * 65536u +
                           (size_t)(R & 255) * 256;
    const int tid = threadIdx.x;
    const int kend = (rt + 1) << 8;

    float vals[8];
    float m = -3.0e38f;
    int cnt = 0;
    for (int k = tid; k < kend; k += 256) {
        float s = Sp[rowbase + (size_t)(k >> 8) * 65536u + (k & 255)];
        vals[cnt++] = s;
        if (k <= R) m = fmaxf(m, s);
    }
    __shared__ float red[4];
#pragma unroll
    for (int o = 32; o > 0; o >>= 1) m = fmaxf(m, __shfl_xor(m, o));
    if ((tid & 63) == 0) red[tid >> 6] = m;
    __syncthreads();
    m = fmaxf(fmaxf(red[0], red[1]), fmaxf(red[2], red[3]));
    __syncthreads();

    float l = 0.0f;
    cnt = 0;
    for (int k = tid; k < kend; k += 256) {
        float e = (k <= R) ? __expf(vals[cnt] - m) : 0.0f;
        vals[cnt] = e;
        ++cnt;
        l += e;
    }
#pragma unroll
    for (int o = 32; o > 0; o >>= 1) l += __shfl_xor(l, o);
    if ((tid & 63) == 0) red[tid >> 6] = l;
    __syncthreads();
    l = red[0] + red[1] + red[2] + red[3];
    const float inv = 1.0f / l;

    cnt = 0;
    for (int k = tid; k < kend; k += 256)
        Pp[rowbase + (size_t)(k >> 8) * 65536u + (k & 255)] = f2bf(vals[cnt++] * inv);
}

// ---------------------------------------------------------------------------
extern "C" void kernel_launch(void* const* d_in, const int* in_sizes, int n_in,
                              void* d_out, int out_size, void* d_ws, size_t ws_size,
                              hipStream_t stream) {
    const float* x  = (const float*)d_in[0];
    const float* Wq = (const float*)d_in[1];
    const float* Wk = (const float*)d_in[2];
    const float* Wv = (const float*)d_in[3];
    float* out = (float*)d_out;

    char* base = (char*)d_ws;
    unsigned short* Qb = (unsigned short*)(base);
    unsigned short* Kb = (unsigned short*)(base + 33554432u);
    unsigned short* Vt = (unsigned short*)(base + 67108864u);
    unsigned short* Xb = (unsigned short*)(base + 100663296u);
    unsigned short* Wt = (unsigned short*)(base + 134217728u);
    float*          Sp = (float*)         (base + 100663296u);   // overlays Xb/Wt
    unsigned short* Pp = (unsigned short*)(base + 176160768u);

    hipFuncSetAttribute(reinterpret_cast<const void*>(&gemm256),
                        hipFuncAttributeMaxDynamicSharedMemorySize, 131072);

    convert_x<<<16384, 256, 0, stream>>>(x, Xb);
    convert_w<<<dim3(32, 32, 3), dim3(32, 8), 0, stream>>>(Wq, Wk, Wv, Wt);
    gemm256<<<dim3(64, 12), 512, 131072, stream>>>(Xb, Wt, Qb, Kb, Vt);
    gemm_attn<1><<<dim3(8, 16, 8), 512, 0, stream>>>(Qb, Kb, Sp);
    softmax_rows<<<dim3(2048, 8), 256, 0, stream>>>(Sp, Pp);
    gemm_attn<2><<<512, 512, 0, stream>>>(Pp, Vt, out);
}